// Round 4
// baseline (615.411 us; speedup 1.0000x reference)
//
#include <hip/hip_runtime.h>
#include <hip/hip_cooperative_groups.h>
#include <math.h>

namespace cg = cooperative_groups;

#define NN 2048
#define BB 4
#define HD 128
#define CNUM 8
#define GRID 1024           // 4 blocks/CU x 256 CUs -- co-residency guaranteed by launch_bounds
#define NTH 256
#define NCH 256             // pool chunks per batch (8 nodes each)
#define ZF4 ((2 * BB * NN * HD + BB * NN) / 4)   // float4 count of [Z1|Z2|dv] zero region

typedef unsigned long long u64;

// Branchless top-3: packed key (float-bits(sq) << 32) | j. sq >= 0 so IEEE
// bits are monotonic; u64 order == (sq, j) lexicographic == reference
// tie-break (lowest j wins).
__device__ __forceinline__ u64 pack_key(float sq, int j) {
    return ((u64)__float_as_uint(sq) << 32) | (unsigned)j;
}
__device__ __forceinline__ void ins3(u64 k, u64& k0, u64& k1, u64& k2) {
    u64 a = k  < k2 ? k  : k2;   // survivor of {k, k2}
    u64 b = k0 > a  ? k0 : a;    // merge a into sorted (k0, k1)
    k0    = k0 < a  ? k0 : a;
    k2    = k1 > b  ? k1 : b;
    k1    = k1 < b  ? k1 : b;
}

// Single cooperative kernel: zero+prep | dist | conv1 | conv2 | pool | cls,
// separated by grid.sync(). Replaces 7 serialized dispatches (~10 us gap each)
// with ~2 us grid barriers. Conv phases use the round-0 PROVEN scatter math.
__global__ __launch_bounds__(NTH, 4) void k_mega(
        const float* __restrict__ x,  const float* __restrict__ W1,
        const float* __restrict__ b1, const float* __restrict__ Wc,
        const float* __restrict__ bc, float* __restrict__ out,
        float4* __restrict__ pts, float* __restrict__ dv,
        float* __restrict__ de,  int* __restrict__ idx,
        float* __restrict__ vals, float* __restrict__ Z1,
        float* __restrict__ Z2,  float* __restrict__ pmax,
        float4* __restrict__ zbase) {
    cg::grid_group grid = cg::this_grid();
    __shared__ float sh[2][HD];
    const int gtid = blockIdx.x * NTH + threadIdx.x;     // [0, 262144)

    // ---- phase 0: zero [Z1|Z2|dv] (8.4 MB) + pack pts -------------------
    for (int u = gtid; u < ZF4; u += GRID * NTH)
        zbase[u] = make_float4(0.f, 0.f, 0.f, 0.f);
    if (gtid < BB * NN) {
        const float a = x[3 * gtid], c = x[3 * gtid + 1], d = x[3 * gtid + 2];
        pts[gtid] = make_float4(a, c, d, a * a + c * c + d * d);
    }
    grid.sync();

    // ---- phase 1: KNN + incidence (one wave per center, 2 centers/wave) --
    {
        const int wgl  = (blockIdx.x << 2) + (threadIdx.x >> 6);  // [0,4096)
        const int lane = threadIdx.x & 63;
        for (int cc = 0; cc < 2; ++cc) {
            const int c = wgl * 2 + cc;                 // [0, 8192)
            const int b = c >> 11, i = c & (NN - 1);
            const float4* pb = pts + b * NN;
            const float4 ci = pb[i];
            u64 k0 = ~0ull, k1 = ~0ull, k2 = ~0ull;
            float dsA = 0.f, dsB = 0.f;
            for (int t = lane; t < NN; t += 256) {      // 8 iters, 4 elems each
                const float4 pa = pb[t];
                const float4 pv = pb[t + 64];
                const float4 pc = pb[t + 128];
                const float4 pd = pb[t + 192];
                const float qa = fmaxf(ci.w + pa.w - 2.0f * (ci.x * pa.x + ci.y * pa.y + ci.z * pa.z), 0.0f);
                const float qb = fmaxf(ci.w + pv.w - 2.0f * (ci.x * pv.x + ci.y * pv.y + ci.z * pv.z), 0.0f);
                const float qc = fmaxf(ci.w + pc.w - 2.0f * (ci.x * pc.x + ci.y * pc.y + ci.z * pc.z), 0.0f);
                const float qd = fmaxf(ci.w + pd.w - 2.0f * (ci.x * pd.x + ci.y * pd.y + ci.z * pd.z), 0.0f);
                dsA += __builtin_amdgcn_sqrtf(qa + 1e-12f) + __builtin_amdgcn_sqrtf(qc + 1e-12f);
                dsB += __builtin_amdgcn_sqrtf(qb + 1e-12f) + __builtin_amdgcn_sqrtf(qd + 1e-12f);
                ins3(pack_key(qa, t),       k0, k1, k2);
                ins3(pack_key(qb, t + 64),  k0, k1, k2);
                ins3(pack_key(qc, t + 128), k0, k1, k2);
                ins3(pack_key(qd, t + 192), k0, k1, k2);
            }
            float dsum = dsA + dsB;
            for (int off = 32; off > 0; off >>= 1) {    // butterfly merge
                const u64 o0 = __shfl_xor(k0, off);
                const u64 o1 = __shfl_xor(k1, off);
                const u64 o2 = __shfl_xor(k2, off);
                dsum += __shfl_xor(dsum, off);
                ins3(o0, k0, k1, k2);
                ins3(o1, k0, k1, k2);
                ins3(o2, k0, k1, k2);
            }
            if (lane == 0) {
                const float s0 = __uint_as_float((unsigned)(k0 >> 32));
                const float s1 = __uint_as_float((unsigned)(k1 >> 32));
                const float s2 = __uint_as_float((unsigned)(k2 >> 32));
                const int   i0 = (int)(k0 & 0xffffffffu);
                const int   i1 = (int)(k1 & 0xffffffffu);
                const int   i2 = (int)(k2 & 0xffffffffu);
                const float avg = dsum * (1.0f / NN);
                const float inva2 = 1.0f / (avg * avg);
                const float v0 = expf(-s0 * inva2);
                const float v1 = expf(-s1 * inva2);
                const float v2 = expf(-s2 * inva2);
                const int base = (b * NN + i) * 3;
                idx[base] = i0; idx[base + 1] = i1; idx[base + 2] = i2;
                vals[base] = v0; vals[base + 1] = v1; vals[base + 2] = v2;
                de[b * NN + i] = v0 + v1 + v2;
                atomicAdd(&dv[b * NN + i0], v0);
                atomicAdd(&dv[b * NN + i1], v1);
                atomicAdd(&dv[b * NN + i2], v2);
            }
        }
    }
    grid.sync();

    // ---- phase 2: conv1 scatter  Z1 += H diag(..) H^T W1 ----------------
    {
        const int h = threadIdx.x & (HD - 1);
        for (int s = 0; s < 4; ++s) {
            const int job = s * 2048 + (blockIdx.x << 1) + (threadIdx.x >> 7);
            const int b = job >> 11, e = job & (NN - 1);
            const int base = (b * NN + e) * 3;
            const int j0 = idx[base], j1 = idx[base + 1], j2 = idx[base + 2];
            const float v0 = vals[base], v1 = vals[base + 1], v2 = vals[base + 2];
            const float ide = 1.0f / de[b * NN + e];
            const float g0 = v0 * rsqrtf(dv[b * NN + j0]);
            const float g1 = v1 * rsqrtf(dv[b * NN + j1]);
            const float g2 = v2 * rsqrtf(dv[b * NN + j2]);
            const float y = ide * (g0 * W1[j0 * HD + h] + g1 * W1[j1 * HD + h] + g2 * W1[j2 * HD + h]);
            atomicAdd(&Z1[((size_t)(b * NN + j0)) * HD + h], v0 * y);
            atomicAdd(&Z1[((size_t)(b * NN + j1)) * HD + h], v1 * y);
            atomicAdd(&Z1[((size_t)(b * NN + j2)) * HD + h], v2 * y);
        }
    }
    grid.sync();

    // ---- phase 3: conv2 scatter on f1 = dv2*Z1 + b1 ---------------------
    {
        const int h = threadIdx.x & (HD - 1);
        const float bh = b1[h];
        for (int s = 0; s < 4; ++s) {
            const int job = s * 2048 + (blockIdx.x << 1) + (threadIdx.x >> 7);
            const int b = job >> 11, e = job & (NN - 1);
            const int base = (b * NN + e) * 3;
            const int j0 = idx[base], j1 = idx[base + 1], j2 = idx[base + 2];
            const float v0 = vals[base], v1 = vals[base + 1], v2 = vals[base + 2];
            const float ide = 1.0f / de[b * NN + e];
            const float d0 = rsqrtf(dv[b * NN + j0]);
            const float d1 = rsqrtf(dv[b * NN + j1]);
            const float d2 = rsqrtf(dv[b * NN + j2]);
            const float f0 = d0 * Z1[((size_t)(b * NN + j0)) * HD + h] + bh;
            const float f1 = d1 * Z1[((size_t)(b * NN + j1)) * HD + h] + bh;
            const float f2 = d2 * Z1[((size_t)(b * NN + j2)) * HD + h] + bh;
            const float y = ide * (v0 * d0 * f0 + v1 * d1 * f1 + v2 * d2 * f2);
            atomicAdd(&Z2[((size_t)(b * NN + j0)) * HD + h], v0 * y);
            atomicAdd(&Z2[((size_t)(b * NN + j1)) * HD + h], v1 * y);
            atomicAdd(&Z2[((size_t)(b * NN + j2)) * HD + h], v2 * y);
        }
    }
    grid.sync();

    // ---- phase 4: partial max over 8-node chunks ------------------------
    {
        const int b = blockIdx.x >> 8, nb = blockIdx.x & (NCH - 1);
        const int sub = threadIdx.x >> 7, h = threadIdx.x & (HD - 1);
        float mx = -INFINITY;
        for (int t = 0; t < 4; ++t) {
            const int v = nb * 8 + t * 2 + sub;
            mx = fmaxf(mx, rsqrtf(dv[b * NN + v]) * Z2[((size_t)(b * NN + v)) * HD + h]);
        }
        sh[sub][h] = mx;
        __syncthreads();
        if (sub == 0)
            pmax[((size_t)(b * NCH + nb)) * HD + h] = fmaxf(sh[0][h], sh[1][h]);
    }
    grid.sync();

    // ---- phase 5: merge chunk maxes + classifier (blocks 0..3) ----------
    if (blockIdx.x < BB) {
        const int b = blockIdx.x;
        const int h = threadIdx.x & (HD - 1), half = threadIdx.x >> 7;
        float mx = -INFINITY;
        for (int c2 = half; c2 < NCH; c2 += 2)
            mx = fmaxf(mx, pmax[((size_t)(b * NCH + c2)) * HD + h]);
        sh[half][h] = mx;
        __syncthreads();
        if (half == 0) sh[0][h] = fmaxf(sh[0][h], sh[1][h]);
        __syncthreads();
        if (threadIdx.x < CNUM) {
            float acc = bc[threadIdx.x];
            for (int q = 0; q < HD; ++q) acc += sh[0][q] * Wc[q * CNUM + threadIdx.x];
            out[b * CNUM + threadIdx.x] = acc;
        }
    }
}

extern "C" void kernel_launch(void* const* d_in, const int* in_sizes, int n_in,
                              void* d_out, int out_size, void* d_ws, size_t ws_size,
                              hipStream_t stream) {
    const float* x  = (const float*)d_in[0];   // [B,N,3]
    const float* W1 = (const float*)d_in[1];   // [N,H1]
    const float* b1 = (const float*)d_in[2];   // [H1]
    const float* Wc = (const float*)d_in[3];   // [H1,C]
    const float* bc = (const float*)d_in[4];   // [C]
    float* out = (float*)d_out;                // [B,C]

    float*  ws   = (float*)d_ws;
    float*  Z1   = ws;                                   // B*N*HD (zeroed in-kernel)
    float*  Z2   = Z1 + (size_t)BB * NN * HD;            // B*N*HD (zeroed in-kernel)
    float*  dv   = Z2 + (size_t)BB * NN * HD;            // B*N    (zeroed in-kernel)
    float4* pts  = (float4*)(dv + BB * NN);              // B*N float4 (16B-aligned offset)
    float*  de   = (float*)(pts + BB * NN);              // B*N
    int*    idx  = (int*)(de + BB * NN);                 // B*N*3
    float*  vals = (float*)(idx + BB * NN * 3);          // B*N*3
    float*  pmax = vals + BB * NN * 3;                   // B*NCH*HD
    float4* zbase = (float4*)Z1;                         // zero region [Z1|Z2|dv]

    void* args[] = {(void*)&x, (void*)&W1, (void*)&b1, (void*)&Wc, (void*)&bc,
                    (void*)&out, (void*)&pts, (void*)&dv, (void*)&de, (void*)&idx,
                    (void*)&vals, (void*)&Z1, (void*)&Z2, (void*)&pmax, (void*)&zbase};
    hipLaunchCooperativeKernel((void*)k_mega, dim3(GRID), dim3(NTH), args, 0, stream);
}

// Round 5
// 128.570 us; speedup vs baseline: 4.7866x; 4.7866x over previous
//
#include <hip/hip_runtime.h>
#include <math.h>

#define NN 2048
#define BB 4
#define HD 128
#define CNUM 8
#define WPB 4               // waves (= centers) per block in k_dist
#define CAP 64              // reverse-adjacency slots per node (avg in-degree = 3)
#define NPB 4               // nodes per block in k_node2

typedef unsigned long long u64;

// Branchless top-3: packed key (float-bits(sq) << 32) | j. sq >= 0 so IEEE
// bits are monotonic; u64 order == (sq, j) lexicographic == reference
// tie-break (lowest j wins).
__device__ __forceinline__ u64 pack_key(float sq, int j) {
    return ((u64)__float_as_uint(sq) << 32) | (unsigned)j;
}
__device__ __forceinline__ void ins3(u64 k, u64& k0, u64& k1, u64& k2) {
    u64 a = k  < k2 ? k  : k2;   // survivor of {k, k2}
    u64 b = k0 > a  ? k0 : a;    // merge a into sorted (k0, k1)
    k0    = k0 < a  ? k0 : a;
    k2    = k1 > b  ? k1 : b;
    k1    = k1 < b  ? k1 : b;
}

// K0: pack (x,y,z,|p|^2) once to global (L2-resident, 128 KB total).
__global__ void k_prep(const float* __restrict__ x, float4* __restrict__ pts) {
    const int t = blockIdx.x * 256 + threadIdx.x;   // [0, B*NN)
    const float a = x[3 * t], c = x[3 * t + 1], d = x[3 * t + 2];
    pts[t] = make_float4(a, c, d, a * a + c * c + d * d);
}

// K1: one wave per center (proven R0/R1 version) + reverse-adjacency build
// in the lane-0 epilogue (3 tiny int atomics per wave).
__global__ __launch_bounds__(256) void k_dist(
        const float4* __restrict__ pts,
        int* __restrict__ idx, float* __restrict__ vals,
        float* __restrict__ de, float* __restrict__ dv,
        int* __restrict__ cnt, int2* __restrict__ rev) {
    const int b = blockIdx.y;
    const float4* pb = pts + b * NN;
    const int wave = threadIdx.x >> 6;
    const int lane = threadIdx.x & 63;
    const int i = blockIdx.x * WPB + wave;          // this wave's center
    const float4 ci = pb[i];                        // wave-uniform -> broadcast
    u64 k0 = ~0ull, k1 = ~0ull, k2 = ~0ull;
    float dsA = 0.f, dsB = 0.f;
    for (int t = lane; t < NN; t += 256) {          // 8 iterations, 4 elems each
        const float4 pa = pb[t];
        const float4 pv = pb[t + 64];
        const float4 pc = pb[t + 128];
        const float4 pd = pb[t + 192];
        const float qa = fmaxf(ci.w + pa.w - 2.0f * (ci.x * pa.x + ci.y * pa.y + ci.z * pa.z), 0.0f);
        const float qb = fmaxf(ci.w + pv.w - 2.0f * (ci.x * pv.x + ci.y * pv.y + ci.z * pv.z), 0.0f);
        const float qc = fmaxf(ci.w + pc.w - 2.0f * (ci.x * pc.x + ci.y * pc.y + ci.z * pc.z), 0.0f);
        const float qd = fmaxf(ci.w + pd.w - 2.0f * (ci.x * pd.x + ci.y * pd.y + ci.z * pd.z), 0.0f);
        dsA += __builtin_amdgcn_sqrtf(qa + 1e-12f) + __builtin_amdgcn_sqrtf(qc + 1e-12f);
        dsB += __builtin_amdgcn_sqrtf(qb + 1e-12f) + __builtin_amdgcn_sqrtf(qd + 1e-12f);
        ins3(pack_key(qa, t),       k0, k1, k2);
        ins3(pack_key(qb, t + 64),  k0, k1, k2);
        ins3(pack_key(qc, t + 128), k0, k1, k2);
        ins3(pack_key(qd, t + 192), k0, k1, k2);
    }
    float dsum = dsA + dsB;
    // butterfly merge: packed keys are globally unique -> plain u64 merge
    for (int off = 32; off > 0; off >>= 1) {
        const u64 o0 = __shfl_xor(k0, off);
        const u64 o1 = __shfl_xor(k1, off);
        const u64 o2 = __shfl_xor(k2, off);
        dsum += __shfl_xor(dsum, off);
        ins3(o0, k0, k1, k2);
        ins3(o1, k0, k1, k2);
        ins3(o2, k0, k1, k2);
    }
    if (lane == 0) {
        const float s0 = __uint_as_float((unsigned)(k0 >> 32));
        const float s1 = __uint_as_float((unsigned)(k1 >> 32));
        const float s2 = __uint_as_float((unsigned)(k2 >> 32));
        const int   i0 = (int)(k0 & 0xffffffffu);
        const int   i1 = (int)(k1 & 0xffffffffu);
        const int   i2 = (int)(k2 & 0xffffffffu);
        const float avg = dsum * (1.0f / NN);
        const float inva2 = 1.0f / (avg * avg);
        const float v0 = expf(-s0 * inva2);
        const float v1 = expf(-s1 * inva2);
        const float v2 = expf(-s2 * inva2);
        const int base = (b * NN + i) * 3;
        idx[base] = i0; idx[base + 1] = i1; idx[base + 2] = i2;
        vals[base] = v0; vals[base + 1] = v1; vals[base + 2] = v2;
        de[b * NN + i] = v0 + v1 + v2;
        atomicAdd(&dv[b * NN + i0], v0);
        atomicAdd(&dv[b * NN + i1], v1);
        atomicAdd(&dv[b * NN + i2], v2);
        // reverse adjacency: node j <- (edge i, coeff v_ij)
        const int p0 = atomicAdd(&cnt[b * NN + i0], 1);
        if (p0 < CAP) rev[((size_t)(b * NN + i0)) * CAP + p0] = make_int2(i, __float_as_int(v0));
        const int p1 = atomicAdd(&cnt[b * NN + i1], 1);
        if (p1 < CAP) rev[((size_t)(b * NN + i1)) * CAP + p1] = make_int2(i, __float_as_int(v1));
        const int p2 = atomicAdd(&cnt[b * NN + i2], 1);
        if (p2 < CAP) rev[((size_t)(b * NN + i2)) * CAP + p2] = make_int2(i, __float_as_int(v2));
    }
}

// K2: edge stage of conv1 -- P1[e,:] = (1/de_e) * sum_t v_t*w_jt*W1[jt,:].
// This is R0's proven k_conv1 arithmetic with the 3 atomics replaced by one
// dense coalesced store. 2 edges per 256-thread block.
__global__ __launch_bounds__(256) void k_edge1(
        const float* __restrict__ W1, const int* __restrict__ idx,
        const float* __restrict__ vals, const float* __restrict__ de,
        const float* __restrict__ dv, float* __restrict__ P1) {
    const int eg = blockIdx.x * 2 + (threadIdx.x >> 7);   // [0, B*NN)
    const int h = threadIdx.x & (HD - 1);
    const int b = eg >> 11;
    const int base = eg * 3;
    const int j0 = idx[base], j1 = idx[base + 1], j2 = idx[base + 2];
    const float v0 = vals[base], v1 = vals[base + 1], v2 = vals[base + 2];
    const float ide = 1.0f / de[eg];
    const float g0 = v0 * rsqrtf(dv[b * NN + j0]);
    const float g1 = v1 * rsqrtf(dv[b * NN + j1]);
    const float g2 = v2 * rsqrtf(dv[b * NN + j2]);
    P1[(size_t)eg * HD + h] =
        ide * (g0 * W1[j0 * HD + h] + g1 * W1[j1 * HD + h] + g2 * W1[j2 * HD + h]);
}

// K3: node stage of conv1 -- f1[i,:] = w_i * sum_{e in rev(i)} v_ei*P1[e,:] + b1.
// One indirection level (rev entry -> P1 row), pipelined by one entry.
__global__ __launch_bounds__(256) void k_node1(
        const float* __restrict__ b1, const float* __restrict__ dv,
        const int* __restrict__ cnt, const int2* __restrict__ rev,
        const float* __restrict__ P1, float* __restrict__ f1) {
    const int ig = blockIdx.x * 2 + (threadIdx.x >> 7);   // [0, B*NN)
    const int h = threadIdx.x & (HD - 1);
    const int b = ig >> 11;
    const int cn = min(cnt[ig], CAP);                     // >= 1 (own edge)
    const int2* rl = rev + (size_t)ig * CAP;
    float acc = 0.f;
    int2 cur = rl[0];
    for (int s = 0; s < cn; ++s) {
        const int2 nxt = rl[min(s + 1, cn - 1)];
        acc += __int_as_float(cur.y) * P1[((size_t)(b * NN + cur.x)) * HD + h];
        cur = nxt;
    }
    f1[(size_t)ig * HD + h] = rsqrtf(dv[ig]) * acc + b1[h];
}

// K4: edge stage of conv2 -- P2[e,:] = (1/de_e) * sum_t v_t*w_jt*f1[jt,:].
__global__ __launch_bounds__(256) void k_edge2(
        const float* __restrict__ f1, const int* __restrict__ idx,
        const float* __restrict__ vals, const float* __restrict__ de,
        const float* __restrict__ dv, float* __restrict__ P2) {
    const int eg = blockIdx.x * 2 + (threadIdx.x >> 7);
    const int h = threadIdx.x & (HD - 1);
    const int b = eg >> 11;
    const int base = eg * 3;
    const int j0 = idx[base], j1 = idx[base + 1], j2 = idx[base + 2];
    const float v0 = vals[base], v1 = vals[base + 1], v2 = vals[base + 2];
    const float ide = 1.0f / de[eg];
    const float g0 = v0 * rsqrtf(dv[b * NN + j0]);
    const float g1 = v1 * rsqrtf(dv[b * NN + j1]);
    const float g2 = v2 * rsqrtf(dv[b * NN + j2]);
    P2[(size_t)eg * HD + h] =
        ide * (g0 * f1[((size_t)(b * NN + j0)) * HD + h]
             + g1 * f1[((size_t)(b * NN + j1)) * HD + h]
             + g2 * f1[((size_t)(b * NN + j2)) * HD + h]);
}

// K5: node stage of conv2 with fused max-pool (R3's proven atomicMax scheme).
// Monotonic-u32 encoding so zero-initialized pmaxK acts as -inf.
__global__ __launch_bounds__(256) void k_node2(
        const float* __restrict__ dv, const int* __restrict__ cnt,
        const int2* __restrict__ rev, const float* __restrict__ P2,
        unsigned* __restrict__ pmaxK) {
    __shared__ float smx[2][HD];
    const int b = blockIdx.y;
    const int sub = threadIdx.x >> 7;
    const int h = threadIdx.x & (HD - 1);
    float mx = -INFINITY;
    for (int t = 0; t < NPB / 2; ++t) {
        const int i = blockIdx.x * NPB + t * 2 + sub;
        const int ig = b * NN + i;
        const int cn = min(cnt[ig], CAP);
        const int2* rl = rev + (size_t)ig * CAP;
        float acc = 0.f;
        int2 cur = rl[0];
        for (int s = 0; s < cn; ++s) {
            const int2 nxt = rl[min(s + 1, cn - 1)];
            acc += __int_as_float(cur.y) * P2[((size_t)(b * NN + cur.x)) * HD + h];
            cur = nxt;
        }
        mx = fmaxf(mx, rsqrtf(dv[ig]) * acc);
    }
    smx[sub][h] = mx;
    __syncthreads();
    if (sub == 0) {
        const float v = fmaxf(smx[0][h], smx[1][h]);
        unsigned u = __float_as_uint(v);
        u = (u & 0x80000000u) ? ~u : (u | 0x80000000u);   // monotonic encode
        atomicMax(&pmaxK[b * HD + h], u);
    }
}

// K6: decode max keys + classifier. grid B x 128 threads.
__global__ void k_cls(const float* __restrict__ Wc, const float* __restrict__ bc,
                      const unsigned* __restrict__ pmaxK, float* __restrict__ out) {
    __shared__ float smax[HD];
    const int b = blockIdx.x, h = threadIdx.x;
    unsigned u = pmaxK[b * HD + h];
    u = (u & 0x80000000u) ? (u ^ 0x80000000u) : ~u;       // decode
    smax[h] = __uint_as_float(u);
    __syncthreads();
    if (h < CNUM) {
        float acc = bc[h];
        for (int q = 0; q < HD; ++q) acc += smax[q] * Wc[q * CNUM + h];
        out[b * CNUM + h] = acc;
    }
}

extern "C" void kernel_launch(void* const* d_in, const int* in_sizes, int n_in,
                              void* d_out, int out_size, void* d_ws, size_t ws_size,
                              hipStream_t stream) {
    const float* x  = (const float*)d_in[0];   // [B,N,3]
    const float* W1 = (const float*)d_in[1];   // [N,H1]
    const float* b1 = (const float*)d_in[2];   // [H1]
    const float* Wc = (const float*)d_in[3];   // [H1,C]
    const float* bc = (const float*)d_in[4];   // [C]
    float* out = (float*)d_out;                // [B,C]

    float4*   pts   = (float4*)d_ws;                       // B*N float4
    float*    dv    = (float*)(pts + BB * NN);             // B*N   (zeroed)
    int*      cnt   = (int*)(dv + BB * NN);                // B*N   (zeroed)
    unsigned* pmaxK = (unsigned*)(cnt + BB * NN);          // B*HD  (zeroed)
    float*    de    = (float*)(pmaxK + BB * HD);           // B*N
    int*      idx   = (int*)(de + BB * NN);                // B*N*3
    float*    vals  = (float*)(idx + BB * NN * 3);         // B*N*3
    int2*     rev   = (int2*)(vals + BB * NN * 3);         // B*N*CAP (8B-aligned)
    float*    P1    = (float*)(rev + (size_t)BB * NN * CAP); // B*N*HD
    float*    f1    = P1 + (size_t)BB * NN * HD;           // B*N*HD
    float*    P2    = f1 + (size_t)BB * NN * HD;           // B*N*HD

    // zero [dv | cnt | pmaxK] (66 KB)
    hipMemsetAsync(dv, 0, (size_t)(2 * BB * NN + BB * HD) * sizeof(float), stream);

    k_prep <<<BB * NN / 256, 256, 0, stream>>>(x, pts);
    k_dist <<<dim3(NN / WPB, BB), 256, 0, stream>>>(pts, idx, vals, de, dv, cnt, rev);
    k_edge1<<<BB * NN / 2, 256, 0, stream>>>(W1, idx, vals, de, dv, P1);
    k_node1<<<BB * NN / 2, 256, 0, stream>>>(b1, dv, cnt, rev, P1, f1);
    k_edge2<<<BB * NN / 2, 256, 0, stream>>>(f1, idx, vals, de, dv, P2);
    k_node2<<<dim3(NN / NPB, BB), 256, 0, stream>>>(dv, cnt, rev, P2, pmaxK);
    k_cls  <<<BB, HD, 0, stream>>>(Wc, bc, pmaxK, out);
}

// Round 6
// 120.563 us; speedup vs baseline: 5.1045x; 1.0664x over previous
//
#include <hip/hip_runtime.h>
#include <math.h>

#define NN 2048
#define BB 4
#define HD 128
#define CNUM 8
#define WPB 4               // waves (= centers) per block in k_dist
#define PCHUNK 64           // nodes per block in k_pool1
#define NCHUNKS (NN / PCHUNK)

typedef unsigned long long u64;

// Branchless top-3: packed key (float-bits(sq) << 32) | j. sq >= 0 so IEEE
// bits are monotonic; u64 order == (sq, j) lexicographic == reference
// tie-break (lowest j wins). 5 min/max per candidate, no divergence.
__device__ __forceinline__ u64 pack_key(float sq, int j) {
    return ((u64)__float_as_uint(sq) << 32) | (unsigned)j;
}
__device__ __forceinline__ void ins3(u64 k, u64& k0, u64& k1, u64& k2) {
    u64 a = k  < k2 ? k  : k2;   // survivor of {k, k2}
    u64 b = k0 > a  ? k0 : a;    // merge a into sorted (k0, k1)
    k0    = k0 < a  ? k0 : a;
    k2    = k1 > b  ? k1 : b;
    k1    = k1 < b  ? k1 : b;
}

// K1: one wave per center. Points staged ONCE per block into LDS (fuses the
// old k_prep): replaces 4x re-stream of the same 32KB through L1 with
// conflict-free ds_read_b128, and drops one dispatch. Arithmetic identical
// to the proven R0 kernel (bit-exact).
__global__ __launch_bounds__(256) void k_dist(
        const float* __restrict__ x,
        int* __restrict__ idx, float* __restrict__ vals,
        float* __restrict__ de, float* __restrict__ dv) {
    __shared__ float4 sp[NN];                       // 32 KB
    const int b = blockIdx.y;
    const float* xb = x + (size_t)b * NN * 3;
    for (int q = threadIdx.x; q < NN; q += 256) {   // stage + pack |p|^2
        const float a = xb[3 * q], c = xb[3 * q + 1], d = xb[3 * q + 2];
        sp[q] = make_float4(a, c, d, a * a + c * c + d * d);
    }
    __syncthreads();

    const int wave = threadIdx.x >> 6;
    const int lane = threadIdx.x & 63;
    const int i = blockIdx.x * WPB + wave;          // this wave's center
    const float4 ci = sp[i];
    u64 k0 = ~0ull, k1 = ~0ull, k2 = ~0ull;
    float dsA = 0.f, dsB = 0.f;
    for (int t = lane; t < NN; t += 256) {          // 8 iterations, 4 elems each
        const float4 pa = sp[t];
        const float4 pv = sp[t + 64];
        const float4 pc = sp[t + 128];
        const float4 pd = sp[t + 192];
        const float qa = fmaxf(ci.w + pa.w - 2.0f * (ci.x * pa.x + ci.y * pa.y + ci.z * pa.z), 0.0f);
        const float qb = fmaxf(ci.w + pv.w - 2.0f * (ci.x * pv.x + ci.y * pv.y + ci.z * pv.z), 0.0f);
        const float qc = fmaxf(ci.w + pc.w - 2.0f * (ci.x * pc.x + ci.y * pc.y + ci.z * pc.z), 0.0f);
        const float qd = fmaxf(ci.w + pd.w - 2.0f * (ci.x * pd.x + ci.y * pd.y + ci.z * pd.z), 0.0f);
        dsA += __builtin_amdgcn_sqrtf(qa + 1e-12f) + __builtin_amdgcn_sqrtf(qc + 1e-12f);
        dsB += __builtin_amdgcn_sqrtf(qb + 1e-12f) + __builtin_amdgcn_sqrtf(qd + 1e-12f);
        ins3(pack_key(qa, t),       k0, k1, k2);
        ins3(pack_key(qb, t + 64),  k0, k1, k2);
        ins3(pack_key(qc, t + 128), k0, k1, k2);
        ins3(pack_key(qd, t + 192), k0, k1, k2);
    }
    float dsum = dsA + dsB;
    // butterfly merge: packed keys are globally unique -> plain u64 merge
    for (int off = 32; off > 0; off >>= 1) {
        const u64 o0 = __shfl_xor(k0, off);
        const u64 o1 = __shfl_xor(k1, off);
        const u64 o2 = __shfl_xor(k2, off);
        dsum += __shfl_xor(dsum, off);
        ins3(o0, k0, k1, k2);
        ins3(o1, k0, k1, k2);
        ins3(o2, k0, k1, k2);
    }
    if (lane == 0) {
        const float s0 = __uint_as_float((unsigned)(k0 >> 32));
        const float s1 = __uint_as_float((unsigned)(k1 >> 32));
        const float s2 = __uint_as_float((unsigned)(k2 >> 32));
        const int   i0 = (int)(k0 & 0xffffffffu);
        const int   i1 = (int)(k1 & 0xffffffffu);
        const int   i2 = (int)(k2 & 0xffffffffu);
        const float avg = dsum * (1.0f / NN);
        const float inva2 = 1.0f / (avg * avg);
        const float v0 = expf(-s0 * inva2);
        const float v1 = expf(-s1 * inva2);
        const float v2 = expf(-s2 * inva2);
        const int base = (b * NN + i) * 3;
        idx[base] = i0; idx[base + 1] = i1; idx[base + 2] = i2;
        vals[base] = v0; vals[base + 1] = v1; vals[base + 2] = v2;
        de[b * NN + i] = v0 + v1 + v2;
        atomicAdd(&dv[b * NN + i0], v0);
        atomicAdd(&dv[b * NN + i1], v1);
        atomicAdd(&dv[b * NN + i2], v2);
    }
}

// K2: first G-application on W1. 256-thread blocks, 2 edges per block.
// (R0-proven scatter: atomics beat every gather variant benched.)
__global__ void k_conv1(const float* __restrict__ W1, const int* __restrict__ idx,
                        const float* __restrict__ vals, const float* __restrict__ de,
                        const float* __restrict__ dv, float* __restrict__ Z1) {
    const int e = blockIdx.x * 2 + (threadIdx.x >> 7);
    const int b = blockIdx.y, h = threadIdx.x & (HD - 1);
    const int base = (b * NN + e) * 3;
    const int j0 = idx[base], j1 = idx[base + 1], j2 = idx[base + 2];
    const float v0 = vals[base], v1 = vals[base + 1], v2 = vals[base + 2];
    const float ide = 1.0f / de[b * NN + e];
    const float g0 = v0 * rsqrtf(dv[b * NN + j0]);
    const float g1 = v1 * rsqrtf(dv[b * NN + j1]);
    const float g2 = v2 * rsqrtf(dv[b * NN + j2]);
    const float y = ide * (g0 * W1[j0 * HD + h] + g1 * W1[j1 * HD + h] + g2 * W1[j2 * HD + h]);
    atomicAdd(&Z1[((size_t)(b * NN + j0)) * HD + h], v0 * y);
    atomicAdd(&Z1[((size_t)(b * NN + j1)) * HD + h], v1 * y);
    atomicAdd(&Z1[((size_t)(b * NN + j2)) * HD + h], v2 * y);
}

// K3: second G-application on f1 = dv2*Z1 + b1.
__global__ void k_conv2(const float* __restrict__ b1, const int* __restrict__ idx,
                        const float* __restrict__ vals, const float* __restrict__ de,
                        const float* __restrict__ dv, const float* __restrict__ Z1,
                        float* __restrict__ Z2) {
    const int e = blockIdx.x * 2 + (threadIdx.x >> 7);
    const int b = blockIdx.y, h = threadIdx.x & (HD - 1);
    const int base = (b * NN + e) * 3;
    const int j0 = idx[base], j1 = idx[base + 1], j2 = idx[base + 2];
    const float v0 = vals[base], v1 = vals[base + 1], v2 = vals[base + 2];
    const float ide = 1.0f / de[b * NN + e];
    const float bh = b1[h];
    const float d0 = rsqrtf(dv[b * NN + j0]);
    const float d1 = rsqrtf(dv[b * NN + j1]);
    const float d2 = rsqrtf(dv[b * NN + j2]);
    const float f0 = d0 * Z1[((size_t)(b * NN + j0)) * HD + h] + bh;
    const float f1 = d1 * Z1[((size_t)(b * NN + j1)) * HD + h] + bh;
    const float f2 = d2 * Z1[((size_t)(b * NN + j2)) * HD + h] + bh;
    const float y = ide * (v0 * d0 * f0 + v1 * d1 * f1 + v2 * d2 * f2);
    atomicAdd(&Z2[((size_t)(b * NN + j0)) * HD + h], v0 * y);
    atomicAdd(&Z2[((size_t)(b * NN + j1)) * HD + h], v1 * y);
    atomicAdd(&Z2[((size_t)(b * NN + j2)) * HD + h], v2 * y);
}

// K4a: partial max over 64-node chunks. grid (B, 32) x 128 threads.
__global__ void k_pool1(const float* __restrict__ dv, const float* __restrict__ Z2,
                        float* __restrict__ pmax) {
    const int b = blockIdx.x, ch = blockIdx.y, h = threadIdx.x;
    const int v0 = ch * PCHUNK;
    float mx = -INFINITY;
    for (int v = v0; v < v0 + PCHUNK; ++v) {
        const float d2 = rsqrtf(dv[b * NN + v]);
        mx = fmaxf(mx, d2 * Z2[((size_t)(b * NN + v)) * HD + h]);
    }
    pmax[(b * NCHUNKS + ch) * HD + h] = mx;
}

// K4b: merge partial maxes + classifier. grid B x 128 threads.
__global__ void k_pool2(const float* __restrict__ Wc, const float* __restrict__ bc,
                        const float* __restrict__ pmax, float* __restrict__ out) {
    __shared__ float smax[HD];
    const int b = blockIdx.x, h = threadIdx.x;
    float mx = -INFINITY;
    for (int c = 0; c < NCHUNKS; ++c)
        mx = fmaxf(mx, pmax[(b * NCHUNKS + c) * HD + h]);
    smax[h] = mx;
    __syncthreads();
    if (h < CNUM) {
        float acc = bc[h];
        for (int q = 0; q < HD; ++q) acc += smax[q] * Wc[q * CNUM + h];
        out[b * CNUM + h] = acc;
    }
}

extern "C" void kernel_launch(void* const* d_in, const int* in_sizes, int n_in,
                              void* d_out, int out_size, void* d_ws, size_t ws_size,
                              hipStream_t stream) {
    const float* x  = (const float*)d_in[0];   // [B,N,3]
    const float* W1 = (const float*)d_in[1];   // [N,H1]
    const float* b1 = (const float*)d_in[2];   // [H1]
    const float* Wc = (const float*)d_in[3];   // [H1,C]
    const float* bc = (const float*)d_in[4];   // [C]
    float* out = (float*)d_out;                // [B,C]

    float* ws = (float*)d_ws;
    float* dv   = ws;                                  // B*N           (zeroed)
    float* Z1   = dv + BB * NN;                        // B*N*HD        (zeroed)
    float* Z2   = Z1 + (size_t)BB * NN * HD;           // B*N*HD        (zeroed)
    float* vals = Z2 + (size_t)BB * NN * HD;           // B*N*3
    float* de   = vals + BB * NN * 3;                  // B*N
    int*   idx  = (int*)(de + BB * NN);                // B*N*3
    float* pmax = (float*)(idx + BB * NN * 3);         // B*32*HD

    // zero the contiguous [dv | Z1 | Z2] region
    hipMemsetAsync(dv, 0, (size_t)(BB * NN) * (1 + 2 * HD) * sizeof(float), stream);

    k_dist<<<dim3(NN / WPB, BB), 256, 0, stream>>>(x, idx, vals, de, dv);
    k_conv1<<<dim3(NN / 2, BB), 256, 0, stream>>>(W1, idx, vals, de, dv, Z1);
    k_conv2<<<dim3(NN / 2, BB), 256, 0, stream>>>(b1, idx, vals, de, dv, Z1, Z2);
    k_pool1<<<dim3(BB, NCHUNKS), HD, 0, stream>>>(dv, Z2, pmax);
    k_pool2<<<BB, HD, 0, stream>>>(Wc, bc, pmax, out);
}